// Round 3
// baseline (58305.396 us; speedup 1.0000x reference)
//
#include <hip/hip_runtime.h>

#define TT   1024
#define BB   64
#define DIN  256
#define HH   512
#define DOUT 256

#define NWG_L0  128
#define NWG_L1  128
#define NWG_OUT 32
#define NWG_TOT 288
#define JH 4
#define KC 64
#define LDSW 68       // padded LDS row stride (floats); 272B keeps float4 rows 16B-aligned
#define NBARRIERS (1 + (TT + 2))

__device__ float g_h1ring[2][BB][HH];
__device__ float g_h2ring[2][BB][HH];

// replay-safe epoch barrier state (zero-initialized at module load)
__device__ unsigned g_arrive[NWG_TOT * 16];   // one u32 per 64B line
__device__ unsigned g_release;
__device__ unsigned g_epoch_base;

__device__ __forceinline__ void gridbar(unsigned e, int wg, int tid) {
    __syncthreads();  // emits s_waitcnt vmcnt(0): all block stores complete
    if (tid == 0)     // publish arrival; RELEASE at agent scope -> L2 writeback of h-stores
        __hip_atomic_store(&g_arrive[wg * 16], e, __ATOMIC_RELEASE, __HIP_MEMORY_SCOPE_AGENT);
    if (wg == 0) {
        for (int s = tid; s < NWG_TOT; s += 256) {
            while (__hip_atomic_load(&g_arrive[s * 16], __ATOMIC_RELAXED,
                                     __HIP_MEMORY_SCOPE_AGENT) != e) {}
        }
        __builtin_amdgcn_fence(__ATOMIC_ACQUIRE, "agent");
        __syncthreads();
        if (tid == 0)
            __hip_atomic_store(&g_release, e, __ATOMIC_RELEASE, __HIP_MEMORY_SCOPE_AGENT);
    } else {
        if (tid == 0) {
            while (__hip_atomic_load(&g_release, __ATOMIC_RELAXED,
                                     __HIP_MEMORY_SCOPE_AGENT) != e) {}
            __builtin_amdgcn_fence(__ATOMIC_ACQUIRE, "agent");
        }
        __syncthreads();
    }
}

__device__ __forceinline__ float sigf(float v) { return 1.f / (1.f + __expf(-v)); }

template<int L>
__device__ __forceinline__ void layer_step(
    int t, int lw, int tid, int lane, int wave,
    const float* __restrict__ xglob,
    const float* __restrict__ wih, const float* __restrict__ whh,
    const float* __restrict__ bih, const float* __restrict__ bhh,
    float* __restrict__ out,
    float (*lds_in)[LDSW], float (*lds_g)[JH][BB], float (*lds_c)[BB])
{
    constexpr int KIN = (L == 0) ? DIN : HH;
    constexpr int K   = KIN + HH;
    const int j0 = lw * JH;

    const float* xsrc = (L == 0) ? (xglob + (size_t)t * BB * DIN) : &g_h1ring[t & 1][0][0];
    const float* hsrc = (L == 0) ? &g_h1ring[(t + 1) & 1][0][0] : &g_h2ring[(t + 1) & 1][0][0];

    float acc0 = 0.f, acc1 = 0.f, acc2 = 0.f, acc3 = 0.f;

    for (int kb = 0; kb < K; kb += KC) {
        const bool   isx  = (kb < KIN);
        const float* src  = isx ? (xsrc + kb) : (hsrc + (kb - KIN));
        const int    srow = isx ? KIN : HH;

        __syncthreads();
        #pragma unroll
        for (int i = 0; i < (BB * KC) / 256; ++i) {
            const int idx = i * 256 + tid;
            const int b = idx >> 6, kk = idx & 63;
            lds_in[b][kk] = src[b * srow + kk];
        }
        __syncthreads();

        // wave == gate index (i,f,g,o); weight rows are wave-uniform -> scalar loads
        const float* wbase = isx ? wih : whh;
        const int    wst   = isx ? KIN : HH;
        const int    wk    = isx ? kb : (kb - KIN);
        const float* wr0 = wbase + (size_t)(wave * HH + j0 + 0) * wst + wk;
        const float* wr1 = wbase + (size_t)(wave * HH + j0 + 1) * wst + wk;
        const float* wr2 = wbase + (size_t)(wave * HH + j0 + 2) * wst + wk;
        const float* wr3 = wbase + (size_t)(wave * HH + j0 + 3) * wst + wk;

        const float4* vrow = (const float4*)&lds_in[lane][0];
        #pragma unroll
        for (int q = 0; q < KC / 4; ++q) {
            const float4 v = vrow[q];
            acc0 = fmaf(v.w, wr0[4*q+3], fmaf(v.z, wr0[4*q+2], fmaf(v.y, wr0[4*q+1], fmaf(v.x, wr0[4*q+0], acc0))));
            acc1 = fmaf(v.w, wr1[4*q+3], fmaf(v.z, wr1[4*q+2], fmaf(v.y, wr1[4*q+1], fmaf(v.x, wr1[4*q+0], acc1))));
            acc2 = fmaf(v.w, wr2[4*q+3], fmaf(v.z, wr2[4*q+2], fmaf(v.y, wr2[4*q+1], fmaf(v.x, wr2[4*q+0], acc2))));
            acc3 = fmaf(v.w, wr3[4*q+3], fmaf(v.z, wr3[4*q+2], fmaf(v.y, wr3[4*q+1], fmaf(v.x, wr3[4*q+0], acc3))));
        }
    }

    __syncthreads();
    lds_g[wave][0][lane] = acc0;
    lds_g[wave][1][lane] = acc1;
    lds_g[wave][2][lane] = acc2;
    lds_g[wave][3][lane] = acc3;
    __syncthreads();

    // thread (wave, lane) owns hidden unit j = j0+wave, batch b = lane
    const int jj = wave, b = lane, j = j0 + jj;
    const float gi = lds_g[0][jj][b] + bih[0 * HH + j] + bhh[0 * HH + j];
    const float gf = lds_g[1][jj][b] + bih[1 * HH + j] + bhh[1 * HH + j];
    const float gg = lds_g[2][jj][b] + bih[2 * HH + j] + bhh[2 * HH + j];
    const float go = lds_g[3][jj][b] + bih[3 * HH + j] + bhh[3 * HH + j];
    const float co = lds_c[jj][b];
    const float cn = sigf(gf) * co + sigf(gi) * tanhf(gg);
    const float hv = sigf(go) * tanhf(cn);
    lds_c[jj][b] = cn;

    float* hring = (L == 0) ? &g_h1ring[t & 1][0][0] : &g_h2ring[t & 1][0][0];
    hring[b * HH + j] = hv;

    if (t == TT - 1) {
        const size_t base = (size_t)TT * BB * DOUT;
        out[base + (size_t)L * BB * HH + (size_t)b * HH + j] = hv;                       // hn[L]
        out[base + (size_t)2 * BB * HH + (size_t)L * BB * HH + (size_t)b * HH + j] = cn; // cn[L]
    }
}

__device__ __forceinline__ void out_step(
    int t, int lwo, int tid, int lane, int wave,
    const float* __restrict__ wout, const float* __restrict__ bout,
    float* __restrict__ out, float (*lds_in)[LDSW])
{
    const float* hsrc = &g_h2ring[t & 1][0][0];
    const int ow0 = lwo * 8 + wave * 2;
    const int ow1 = ow0 + 1;
    const float* w0 = wout + (size_t)ow0 * HH;
    const float* w1 = wout + (size_t)ow1 * HH;
    float a0 = 0.f, a1 = 0.f;

    for (int kb = 0; kb < HH; kb += KC) {
        __syncthreads();
        #pragma unroll
        for (int i = 0; i < (BB * KC) / 256; ++i) {
            const int idx = i * 256 + tid;
            const int b = idx >> 6, kk = idx & 63;
            lds_in[b][kk] = hsrc[b * HH + kb + kk];
        }
        __syncthreads();
        const float4* vrow = (const float4*)&lds_in[lane][0];
        #pragma unroll
        for (int q = 0; q < KC / 4; ++q) {
            const float4 v = vrow[q];
            a0 = fmaf(v.w, w0[kb+4*q+3], fmaf(v.z, w0[kb+4*q+2], fmaf(v.y, w0[kb+4*q+1], fmaf(v.x, w0[kb+4*q+0], a0))));
            a1 = fmaf(v.w, w1[kb+4*q+3], fmaf(v.z, w1[kb+4*q+2], fmaf(v.y, w1[kb+4*q+1], fmaf(v.x, w1[kb+4*q+0], a1))));
        }
    }
    out[(size_t)t * BB * DOUT + (size_t)lane * DOUT + ow0] = a0 + bout[ow0];
    out[(size_t)t * BB * DOUT + (size_t)lane * DOUT + ow1] = a1 + bout[ow1];
}

extern "C" __global__ void __launch_bounds__(256)
lstm2_fused(const float* __restrict__ x,
            const float* __restrict__ wih0, const float* __restrict__ whh0,
            const float* __restrict__ bih0, const float* __restrict__ bhh0,
            const float* __restrict__ wih1, const float* __restrict__ whh1,
            const float* __restrict__ bih1, const float* __restrict__ bhh1,
            const float* __restrict__ wout, const float* __restrict__ bout,
            float* __restrict__ out)
{
    __shared__ __align__(16) float lds_in[BB][LDSW];
    __shared__ float lds_g[4][JH][BB];
    __shared__ float lds_c[JH][BB];

    const int tid  = threadIdx.x;
    const int lane = tid & 63;
    const int wave = __builtin_amdgcn_readfirstlane(tid >> 6);
    const int wg   = blockIdx.x;

    const unsigned base = __hip_atomic_load(&g_epoch_base, __ATOMIC_RELAXED,
                                            __HIP_MEMORY_SCOPE_AGENT);
    unsigned e = base;

    // zero the t=-1 parity ring buffers + per-WG c state
    {
        float* r1 = &g_h1ring[1][0][0];
        float* r2 = &g_h2ring[1][0][0];
        const int gidx = wg * 256 + tid;
        if (gidx < BB * HH) { r1[gidx] = 0.f; r2[gidx] = 0.f; }
        ((float*)lds_c)[tid] = 0.f;
    }
    gridbar(++e, wg, tid);

    // pipelined super-steps: L0 at t=s, L1 at t=s-1, OUT at t=s-2
    for (int s = 0; s <= TT + 1; ++s) {
        if (wg < NWG_L0) {
            if (s < TT)
                layer_step<0>(s, wg, tid, lane, wave, x, wih0, whh0, bih0, bhh0,
                              out, lds_in, lds_g, lds_c);
        } else if (wg < NWG_L0 + NWG_L1) {
            const int t = s - 1;
            if (t >= 0 && t < TT)
                layer_step<1>(t, wg - NWG_L0, tid, lane, wave, nullptr, wih1, whh1, bih1, bhh1,
                              out, lds_in, lds_g, lds_c);
        } else {
            const int t = s - 2;
            if (t >= 0 && t < TT)
                out_step(t, wg - NWG_L0 - NWG_L1, tid, lane, wave, wout, bout, out, lds_in);
        }
        gridbar(++e, wg, tid);
    }

    // advance the persistent epoch base for the next (replayed) launch
    if (wg == 0 && tid == 0)
        __hip_atomic_store(&g_epoch_base, base + NBARRIERS, __ATOMIC_RELAXED,
                           __HIP_MEMORY_SCOPE_AGENT);
}

extern "C" void kernel_launch(void* const* d_in, const int* in_sizes, int n_in,
                              void* d_out, int out_size, void* d_ws, size_t ws_size,
                              hipStream_t stream) {
    const float* x    = (const float*)d_in[0];
    const float* wih0 = (const float*)d_in[1];
    const float* whh0 = (const float*)d_in[2];
    const float* bih0 = (const float*)d_in[3];
    const float* bhh0 = (const float*)d_in[4];
    const float* wih1 = (const float*)d_in[5];
    const float* whh1 = (const float*)d_in[6];
    const float* bih1 = (const float*)d_in[7];
    const float* bhh1 = (const float*)d_in[8];
    const float* wout = (const float*)d_in[9];
    const float* bout = (const float*)d_in[10];
    float* out = (float*)d_out;

    hipLaunchKernelGGL(lstm2_fused, dim3(NWG_TOT), dim3(256), 0, stream,
                       x, wih0, whh0, bih0, bhh0, wih1, whh1, bih1, bhh1,
                       wout, bout, out);
}

// Round 4
// 27466.977 us; speedup vs baseline: 2.1227x; 2.1227x over previous
//
#include <hip/hip_runtime.h>

#define TT   1024
#define BB   64
#define DIN  256
#define HH   512
#define DOUT 256

#define NWG_L0  64
#define NWG_L1  64
#define NWG_OUT 8
#define NWG_TOT 136
#define NBARRIERS (1 + (TT + 2))

typedef short bf16x8 __attribute__((ext_vector_type(8)));
typedef float f32x4  __attribute__((ext_vector_type(4)));

// frag-ordered bf16 tensors: index f = ((ks*4 + ct)*64 + lane), element e
// value = M[k = ks*32 + (lane>>4)*8 + e][col = ct*16 + (lane&15)]
__device__ bf16x8 g_xf[TT * 2048];     // x packed: 8 ks  x 4 ct x 64 lanes per t (32 MB)
__device__ bf16x8 g_h1f[2][4096];      // h1 ring: 16 ks x 4 ct x 64
__device__ bf16x8 g_h2f[2][4096];      // h2 ring

// replay-safe epoch barrier state (zero-initialized at module load)
__device__ unsigned g_arrive[NWG_TOT * 16];
__device__ unsigned g_release;
__device__ unsigned g_epoch_base;

__device__ __forceinline__ void gridbar(unsigned e, int wg, int tid) {
    __syncthreads();
    if (tid == 0)
        __hip_atomic_store(&g_arrive[wg * 16], e, __ATOMIC_RELEASE, __HIP_MEMORY_SCOPE_AGENT);
    if (wg == 0) {
        for (int s = tid; s < NWG_TOT; s += 128) {
            while (__hip_atomic_load(&g_arrive[s * 16], __ATOMIC_RELAXED,
                                     __HIP_MEMORY_SCOPE_AGENT) != e) {}
        }
        __builtin_amdgcn_fence(__ATOMIC_ACQUIRE, "agent");
        __syncthreads();
        if (tid == 0)
            __hip_atomic_store(&g_release, e, __ATOMIC_RELEASE, __HIP_MEMORY_SCOPE_AGENT);
    } else {
        if (tid == 0) {
            while (__hip_atomic_load(&g_release, __ATOMIC_RELAXED,
                                     __HIP_MEMORY_SCOPE_AGENT) != e) {}
            __builtin_amdgcn_fence(__ATOMIC_ACQUIRE, "agent");
        }
        __syncthreads();
    }
}

__device__ __forceinline__ float sigf(float v) { return 1.f / (1.f + __expf(-v)); }

__device__ __forceinline__ short f2bf(float f) {   // RNE float->bf16 bits
    unsigned u = __builtin_bit_cast(unsigned, f);
    unsigned r = (u + 0x7FFFu + ((u >> 16) & 1u)) >> 16;
    return (short)r;
}

__device__ __forceinline__ bf16x8 pack8(float4 v0, float4 v1) {
    bf16x8 r;
    r[0] = f2bf(v0.x); r[1] = f2bf(v0.y); r[2] = f2bf(v0.z); r[3] = f2bf(v0.w);
    r[4] = f2bf(v1.x); r[5] = f2bf(v1.y); r[6] = f2bf(v1.z); r[7] = f2bf(v1.w);
    return r;
}

// ---------------- pre-pass: pack x (fp32 [T][B][DIN]) into frag-ordered bf16
extern "C" __global__ void __launch_bounds__(256)
pack_x(const float* __restrict__ x) {
    const int t = blockIdx.x, tid = threadIdx.x;
    const float* xt = x + (size_t)t * BB * DIN;
    bf16x8* dst = g_xf + (size_t)t * 2048;
    #pragma unroll
    for (int u = 0; u < 8; ++u) {
        const int f = u * 256 + tid;
        const int lane_ = f & 63, ctks = f >> 6;
        const int ct = ctks & 3, ks = ctks >> 2;
        const int b  = ct * 16 + (lane_ & 15);
        const int kb = ks * 32 + (lane_ >> 4) * 8;
        const float4* s = (const float4*)(xt + b * DIN + kb);
        dst[f] = pack8(s[0], s[1]);
    }
}

// ---------------- LSTM layer role: wave owns 4 hidden units x 4 gates (16 rows)
template<int L>   // L=0: in=[x_t ; h1_{t-1}] K=768; L=1: in=[h1_t ; h2_{t-1}] K=1024
__device__ void run_layer(int wg, int tid,
                          const float* __restrict__ wih, const float* __restrict__ whh,
                          const float* __restrict__ bih, const float* __restrict__ bhh,
                          float* __restrict__ out, unsigned ep)
{
    constexpr int KINX = (L == 0) ? DIN : HH;
    constexpr int NKSX = KINX / 32;          // frags from x-part (8 or 16)
    constexpr int NKSB = HH / 32;            // 16 frags from h-part
    constexpr int NKS  = NKSX + NKSB;

    const int lane = tid & 63, lo = lane & 15, hi = lane >> 4;
    const int wv    = ((L == 0) ? wg : wg - NWG_L0) * 2 + (tid >> 6);
    const int jbase = wv * 4;
    const int grow  = (lo & 3) * HH + jbase + (lo >> 2);   // gate-major weight row (A row = lo)

    // --- load this wave's weights into registers as bf16 A-fragments (once per launch)
    bf16x8 aF[NKS];
    #pragma unroll
    for (int ks = 0; ks < NKS; ++ks) {
        const float* wr;
        if (ks * 32 < KINX) wr = wih + (size_t)grow * KINX + ks * 32 + hi * 8;
        else                wr = whh + (size_t)grow * HH + (ks - NKSX) * 32 + hi * 8;
        const float4* p = (const float4*)wr;
        aF[ks] = pack8(p[0], p[1]);
    }

    f32x4 biasv;
    #pragma unroll
    for (int r = 0; r < 4; ++r)
        biasv[r] = bih[r * HH + jbase + hi] + bhh[r * HH + jbase + hi];

    // h-ring write slot for unit j = jbase+hi, element position inside frag
    const int wksp = wv >> 3, wkhi = (wv >> 1) & 3, wel = (wv & 1) * 4 + hi;

    float cst[4] = {0.f, 0.f, 0.f, 0.f};

    for (int s = 0; s <= TT + 1; ++s) {
        const int t = (L == 0) ? s : s - 1;
        if (t >= 0 && t < TT) {
            const bf16x8* srcA = (L == 0) ? (g_xf + (size_t)t * 2048) : g_h1f[t & 1];
            const bf16x8* srcB = (L == 0) ? g_h1f[(t + 1) & 1] : g_h2f[(t + 1) & 1];

            f32x4 acc[4] = {biasv, biasv, biasv, biasv};
            #pragma unroll
            for (int ks = 0; ks < NKSX; ++ks)
                #pragma unroll
                for (int ct = 0; ct < 4; ++ct)
                    acc[ct] = __builtin_amdgcn_mfma_f32_16x16x32_bf16(
                        aF[ks], srcA[(ks * 4 + ct) * 64 + lane], acc[ct], 0, 0, 0);
            #pragma unroll
            for (int ks = 0; ks < NKSB; ++ks)
                #pragma unroll
                for (int ct = 0; ct < 4; ++ct)
                    acc[ct] = __builtin_amdgcn_mfma_f32_16x16x32_bf16(
                        aF[NKSX + ks], srcB[(ks * 4 + ct) * 64 + lane], acc[ct], 0, 0, 0);

            // lane (hi,lo), quadrant ct: gates i,f,g,o for unit j=jbase+hi, batch b=ct*16+lo
            short* ringW = (short*)((L == 0) ? g_h1f[t & 1] : g_h2f[t & 1]);
            #pragma unroll
            for (int ct = 0; ct < 4; ++ct) {
                const float gi = acc[ct][0], gf = acc[ct][1];
                const float gg = acc[ct][2], go = acc[ct][3];
                const float cn_ = sigf(gf) * cst[ct] + sigf(gi) * tanhf(gg);
                const float hv  = sigf(go) * tanhf(cn_);
                cst[ct] = cn_;
                ringW[(((wksp * 4 + ct) * 64) + wkhi * 16 + lo) * 8 + wel] = f2bf(hv);
                if (t == TT - 1) {
                    const int j = jbase + hi, b = ct * 16 + lo;
                    const size_t base = (size_t)TT * BB * DOUT;
                    out[base + (size_t)L * BB * HH + (size_t)b * HH + j] = hv;
                    out[base + (size_t)2 * BB * HH + (size_t)L * BB * HH + (size_t)b * HH + j] = cn_;
                }
            }
        }
        gridbar(++ep, wg, tid);
    }
}

// ---------------- output projection role: wave owns 16 output dims
__device__ void run_out(int wg, int tid,
                        const float* __restrict__ wout, const float* __restrict__ bout,
                        float* __restrict__ out, unsigned ep)
{
    constexpr int NKS = HH / 32;   // 16
    const int lane = tid & 63, lo = lane & 15, hi = lane >> 4;
    const int wv = (wg - NWG_L0 - NWG_L1) * 2 + (tid >> 6);
    const int obase = wv * 16;

    bf16x8 aF[NKS];
    #pragma unroll
    for (int ks = 0; ks < NKS; ++ks) {
        const float4* p = (const float4*)(wout + (size_t)(obase + lo) * HH + ks * 32 + hi * 8);
        aF[ks] = pack8(p[0], p[1]);
    }
    f32x4 biasv;
    #pragma unroll
    for (int r = 0; r < 4; ++r) biasv[r] = bout[obase + hi * 4 + r];

    for (int s = 0; s <= TT + 1; ++s) {
        const int t = s - 2;
        if (t >= 0 && t < TT) {
            const bf16x8* src = g_h2f[t & 1];
            f32x4 acc[4] = {biasv, biasv, biasv, biasv};
            #pragma unroll
            for (int ks = 0; ks < NKS; ++ks)
                #pragma unroll
                for (int ct = 0; ct < 4; ++ct)
                    acc[ct] = __builtin_amdgcn_mfma_f32_16x16x32_bf16(
                        aF[ks], src[(ks * 4 + ct) * 64 + lane], acc[ct], 0, 0, 0);
            #pragma unroll
            for (int ct = 0; ct < 4; ++ct)
                #pragma unroll
                for (int r = 0; r < 4; ++r) {
                    const int b = ct * 16 + lo, o = obase + hi * 4 + r;
                    out[(size_t)t * BB * DOUT + (size_t)b * DOUT + o] = acc[ct][r];
                }
        }
        gridbar(++ep, wg, tid);
    }
}

extern "C" __global__ void __launch_bounds__(128, 1)
lstm2_fused(const float* __restrict__ x,
            const float* __restrict__ wih0, const float* __restrict__ whh0,
            const float* __restrict__ bih0, const float* __restrict__ bhh0,
            const float* __restrict__ wih1, const float* __restrict__ whh1,
            const float* __restrict__ bih1, const float* __restrict__ bhh1,
            const float* __restrict__ wout, const float* __restrict__ bout,
            float* __restrict__ out)
{
    const int tid = threadIdx.x, wg = blockIdx.x;

    const unsigned base = __hip_atomic_load(&g_epoch_base, __ATOMIC_RELAXED,
                                            __HIP_MEMORY_SCOPE_AGENT);
    unsigned ep = base;

    // zero t=-1 parity ring buffers (h1f[1], h2f[1]) as uint4 lines
    {
        const int gidx = wg * 128 + tid;
        if (gidx < 4096) {
            ((uint4*)g_h1f[1])[gidx] = uint4{0, 0, 0, 0};
            ((uint4*)g_h2f[1])[gidx] = uint4{0, 0, 0, 0};
        }
    }
    gridbar(++ep, wg, tid);

    if (wg < NWG_L0)
        run_layer<0>(wg, tid, wih0, whh0, bih0, bhh0, out, ep);
    else if (wg < NWG_L0 + NWG_L1)
        run_layer<1>(wg, tid, wih1, whh1, bih1, bhh1, out, ep);
    else
        run_out(wg, tid, wout, bout, out, ep);

    if (wg == 0 && tid == 0)
        __hip_atomic_store(&g_epoch_base, base + NBARRIERS, __ATOMIC_RELAXED,
                           __HIP_MEMORY_SCOPE_AGENT);
}

extern "C" void kernel_launch(void* const* d_in, const int* in_sizes, int n_in,
                              void* d_out, int out_size, void* d_ws, size_t ws_size,
                              hipStream_t stream) {
    const float* x    = (const float*)d_in[0];
    const float* wih0 = (const float*)d_in[1];
    const float* whh0 = (const float*)d_in[2];
    const float* bih0 = (const float*)d_in[3];
    const float* bhh0 = (const float*)d_in[4];
    const float* wih1 = (const float*)d_in[5];
    const float* whh1 = (const float*)d_in[6];
    const float* bih1 = (const float*)d_in[7];
    const float* bhh1 = (const float*)d_in[8];
    const float* wout = (const float*)d_in[9];
    const float* bout = (const float*)d_in[10];
    float* out = (float*)d_out;

    hipLaunchKernelGGL(pack_x, dim3(TT), dim3(256), 0, stream, x);
    hipLaunchKernelGGL(lstm2_fused, dim3(NWG_TOT), dim3(128), 0, stream,
                       x, wih0, whh0, bih0, bhh0, wih1, whh1, bih1, bhh1,
                       wout, bout, out);
}

// Round 5
// 8522.797 us; speedup vs baseline: 6.8411x; 3.2228x over previous
//
#include <hip/hip_runtime.h>

#define TT   1024
#define BB   64
#define DIN  256
#define HH   512
#define DOUT 256

#define NWG_L0  32
#define NWG_L1  32
#define NWG_OUT 4
#define NWG_TOT 68
#define NBARRIERS (1 + (TT + 2))

typedef short bf16x8 __attribute__((ext_vector_type(8)));
typedef float f32x4  __attribute__((ext_vector_type(4)));

// frag-ordered bf16 tensors: index f = ((ks*4 + ct)*64 + lane), element e
// value = M[k = ks*32 + (lane>>4)*8 + e][col = ct*16 + (lane&15)]
__device__ bf16x8 g_xf[TT * 2048];     // x packed: 8 ks x 4 ct x 64 lanes per t (32 MB)
__device__ bf16x8 g_h1f[2][4096];      // h1 ring: 16 ks x 4 ct x 64
__device__ bf16x8 g_h2f[2][4096];      // h2 ring

// replay-safe epoch barrier state (zero-initialized at module load)
__device__ unsigned g_arrive[NWG_TOT * 16];
__device__ unsigned g_release;
__device__ unsigned g_epoch_base;

__device__ __forceinline__ void gridbar(unsigned e, int wg, int tid) {
    __syncthreads();
    if (tid == 0)
        __hip_atomic_store(&g_arrive[wg * 16], e, __ATOMIC_RELEASE, __HIP_MEMORY_SCOPE_AGENT);
    if (wg == 0) {
        for (int s = tid; s < NWG_TOT; s += 256) {
            while (__hip_atomic_load(&g_arrive[s * 16], __ATOMIC_RELAXED,
                                     __HIP_MEMORY_SCOPE_AGENT) != e) {}
        }
        __builtin_amdgcn_fence(__ATOMIC_ACQUIRE, "agent");
        __syncthreads();
        if (tid == 0)
            __hip_atomic_store(&g_release, e, __ATOMIC_RELEASE, __HIP_MEMORY_SCOPE_AGENT);
    } else {
        if (tid == 0) {
            while (__hip_atomic_load(&g_release, __ATOMIC_RELAXED,
                                     __HIP_MEMORY_SCOPE_AGENT) != e) {}
            __builtin_amdgcn_fence(__ATOMIC_ACQUIRE, "agent");
        }
        __syncthreads();
    }
}

__device__ __forceinline__ float sigf(float v) { return 1.f / (1.f + __expf(-v)); }
__device__ __forceinline__ float tanh_fast(float v) { return 2.f / (1.f + __expf(-2.f * v)) - 1.f; }

__device__ __forceinline__ short f2bf(float f) {   // RNE float->bf16 bits
    unsigned u = __builtin_bit_cast(unsigned, f);
    unsigned r = (u + 0x7FFFu + ((u >> 16) & 1u)) >> 16;
    return (short)r;
}

__device__ __forceinline__ bf16x8 pack8(float4 v0, float4 v1) {
    bf16x8 r;
    r[0] = f2bf(v0.x); r[1] = f2bf(v0.y); r[2] = f2bf(v0.z); r[3] = f2bf(v0.w);
    r[4] = f2bf(v1.x); r[5] = f2bf(v1.y); r[6] = f2bf(v1.z); r[7] = f2bf(v1.w);
    return r;
}

// ---------------- pre-pass: pack x (fp32 [T][B][DIN]) into frag-ordered bf16
extern "C" __global__ void __launch_bounds__(256)
pack_x(const float* __restrict__ x) {
    const int t = blockIdx.x, tid = threadIdx.x;
    const float* xt = x + (size_t)t * BB * DIN;
    bf16x8* dst = g_xf + (size_t)t * 2048;
    #pragma unroll
    for (int u = 0; u < 8; ++u) {
        const int f = u * 256 + tid;
        const int lane_ = f & 63, ctks = f >> 6;
        const int ct = ctks & 3, ks = ctks >> 2;
        const int b  = ct * 16 + (lane_ & 15);
        const int kb = ks * 32 + (lane_ >> 4) * 8;
        const float4* s = (const float4*)(xt + b * DIN + kb);
        dst[f] = pack8(s[0], s[1]);
    }
}

// ---------------- LSTM layer role: wave owns 4 hidden units x 4 gates (16 rows)
template<int L>   // L=0: in=[x_t ; h1_{t-1}] K=768; L=1: in=[h1_t ; h2_{t-1}] K=1024
__device__ void run_layer(int wg, int tid,
                          const float* __restrict__ wih, const float* __restrict__ whh,
                          const float* __restrict__ bih, const float* __restrict__ bhh,
                          float* __restrict__ out, unsigned ep)
{
    constexpr int KINX = (L == 0) ? DIN : HH;
    constexpr int NKSX = KINX / 32;          // frags from x-part (8 or 16)
    constexpr int NKSB = HH / 32;            // 16 frags from h-part
    constexpr int NKS  = NKSX + NKSB;
    constexpr int NA   = NKSX * 4;           // 32 (L0) or 64 (L1) B-frags, x-part
    constexpr int NB   = NKSB * 4;           // 64 B-frags, h-part

    const int lane = tid & 63, lo = lane & 15, hi = lane >> 4;
    const int wv    = ((L == 0) ? wg : wg - NWG_L0) * 4 + (tid >> 6);
    const int jbase = wv * 4;
    const int grow  = (lo & 3) * HH + jbase + (lo >> 2);   // gate-major weight row (A row = lo)

    // --- this wave's weights as bf16 A-fragments in registers (loaded once)
    bf16x8 aF[NKS];
    #pragma unroll
    for (int ks = 0; ks < NKS; ++ks) {
        const float* wr;
        if (ks * 32 < KINX) wr = wih + (size_t)grow * KINX + ks * 32 + hi * 8;
        else                wr = whh + (size_t)grow * HH + (ks - NKSX) * 32 + hi * 8;
        const float4* p = (const float4*)wr;
        aF[ks] = pack8(p[0], p[1]);
    }

    f32x4 biasv;
    #pragma unroll
    for (int r = 0; r < 4; ++r)
        biasv[r] = bih[r * HH + jbase + hi] + bhh[r * HH + jbase + hi];

    // h-ring write slot for unit j = jbase+hi
    const int wksp = wv >> 3, wkhi = (wv >> 1) & 3, wel = (wv & 1) * 4 + hi;

    float cst[4] = {0.f, 0.f, 0.f, 0.f};

    for (int s = 0; s <= TT + 1; ++s) {
        const int t = (L == 0) ? s : s - 1;
        if (t >= 0 && t < TT) {
            const bf16x8* srcA = (L == 0) ? (g_xf + (size_t)t * 2048) : g_h1f[t & 1];
            const bf16x8* srcB = (L == 0) ? g_h1f[(t + 1) & 1] : g_h2f[(t + 1) & 1];

            f32x4 acc[4] = {biasv, biasv, biasv, biasv};

            // ---- batch 1: issue ALL x-part B-frags, then consume
            {
                bf16x8 ba[NA];
                #pragma unroll
                for (int i = 0; i < NA; ++i) ba[i] = srcA[i * 64 + lane];
                #pragma unroll
                for (int ks = 0; ks < NKSX; ++ks)
                    #pragma unroll
                    for (int ct = 0; ct < 4; ++ct)
                        acc[ct] = __builtin_amdgcn_mfma_f32_16x16x32_bf16(
                            aF[ks], ba[ks * 4 + ct], acc[ct], 0, 0, 0);
            }
            // ---- batch 2: issue ALL h-part B-frags, then consume
            {
                bf16x8 bb[NB];
                #pragma unroll
                for (int i = 0; i < NB; ++i) bb[i] = srcB[i * 64 + lane];
                #pragma unroll
                for (int ks = 0; ks < NKSB; ++ks)
                    #pragma unroll
                    for (int ct = 0; ct < 4; ++ct)
                        acc[ct] = __builtin_amdgcn_mfma_f32_16x16x32_bf16(
                            aF[NKSX + ks], bb[ks * 4 + ct], acc[ct], 0, 0, 0);
            }

            // lane (hi,lo), quadrant ct: gates i,f,g,o for unit j=jbase+hi, batch b=ct*16+lo
            short* ringW = (short*)((L == 0) ? g_h1f[t & 1] : g_h2f[t & 1]);
            #pragma unroll
            for (int ct = 0; ct < 4; ++ct) {
                const float gi = acc[ct][0], gf = acc[ct][1];
                const float gg = acc[ct][2], go = acc[ct][3];
                const float cn_ = sigf(gf) * cst[ct] + sigf(gi) * tanh_fast(gg);
                const float hv  = sigf(go) * tanh_fast(cn_);
                cst[ct] = cn_;
                ringW[(((wksp * 4 + ct) * 64) + wkhi * 16 + lo) * 8 + wel] = f2bf(hv);
                if (t == TT - 1) {
                    const int j = jbase + hi, b = ct * 16 + lo;
                    const size_t base = (size_t)TT * BB * DOUT;
                    out[base + (size_t)L * BB * HH + (size_t)b * HH + j] = hv;
                    out[base + (size_t)2 * BB * HH + (size_t)L * BB * HH + (size_t)b * HH + j] = cn_;
                }
            }
        }
        gridbar(++ep, wg, tid);
    }
}

// ---------------- output projection role: wave owns 16 output dims
__device__ void run_out(int wg, int tid,
                        const float* __restrict__ wout, const float* __restrict__ bout,
                        float* __restrict__ out, unsigned ep)
{
    constexpr int NKS = HH / 32;   // 16
    constexpr int NB  = NKS * 4;   // 64
    const int lane = tid & 63, lo = lane & 15, hi = lane >> 4;
    const int wv = (wg - NWG_L0 - NWG_L1) * 4 + (tid >> 6);
    const int obase = wv * 16;

    bf16x8 aF[NKS];
    #pragma unroll
    for (int ks = 0; ks < NKS; ++ks) {
        const float4* p = (const float4*)(wout + (size_t)(obase + lo) * HH + ks * 32 + hi * 8);
        aF[ks] = pack8(p[0], p[1]);
    }
    f32x4 biasv;
    #pragma unroll
    for (int r = 0; r < 4; ++r) biasv[r] = bout[obase + hi * 4 + r];

    for (int s = 0; s <= TT + 1; ++s) {
        const int t = s - 2;
        if (t >= 0 && t < TT) {
            const bf16x8* src = g_h2f[t & 1];
            f32x4 acc[4] = {biasv, biasv, biasv, biasv};
            {
                bf16x8 bb[NB];
                #pragma unroll
                for (int i = 0; i < NB; ++i) bb[i] = src[i * 64 + lane];
                #pragma unroll
                for (int ks = 0; ks < NKS; ++ks)
                    #pragma unroll
                    for (int ct = 0; ct < 4; ++ct)
                        acc[ct] = __builtin_amdgcn_mfma_f32_16x16x32_bf16(
                            aF[ks], bb[ks * 4 + ct], acc[ct], 0, 0, 0);
            }
            #pragma unroll
            for (int ct = 0; ct < 4; ++ct)
                #pragma unroll
                for (int r = 0; r < 4; ++r) {
                    const int b = ct * 16 + lo, o = obase + hi * 4 + r;
                    out[(size_t)t * BB * DOUT + (size_t)b * DOUT + o] = acc[ct][r];
                }
        }
        gridbar(++ep, wg, tid);
    }
}

extern "C" __global__ void __launch_bounds__(256, 1)
lstm2_fused(const float* __restrict__ x,
            const float* __restrict__ wih0, const float* __restrict__ whh0,
            const float* __restrict__ bih0, const float* __restrict__ bhh0,
            const float* __restrict__ wih1, const float* __restrict__ whh1,
            const float* __restrict__ bih1, const float* __restrict__ bhh1,
            const float* __restrict__ wout, const float* __restrict__ bout,
            float* __restrict__ out)
{
    const int tid = threadIdx.x, wg = blockIdx.x;

    const unsigned base = __hip_atomic_load(&g_epoch_base, __ATOMIC_RELAXED,
                                            __HIP_MEMORY_SCOPE_AGENT);
    unsigned ep = base;

    // zero t=-1 parity ring buffers (h1f[1], h2f[1]) as uint4 lines
    {
        const int gidx = wg * 256 + tid;
        if (gidx < 4096) {
            ((uint4*)g_h1f[1])[gidx] = uint4{0, 0, 0, 0};
            ((uint4*)g_h2f[1])[gidx] = uint4{0, 0, 0, 0};
        }
    }
    gridbar(++ep, wg, tid);

    if (wg < NWG_L0)
        run_layer<0>(wg, tid, wih0, whh0, bih0, bhh0, out, ep);
    else if (wg < NWG_L0 + NWG_L1)
        run_layer<1>(wg, tid, wih1, whh1, bih1, bhh1, out, ep);
    else
        run_out(wg, tid, wout, bout, out, ep);

    if (wg == 0 && tid == 0)
        __hip_atomic_store(&g_epoch_base, base + NBARRIERS, __ATOMIC_RELAXED,
                           __HIP_MEMORY_SCOPE_AGENT);
}

extern "C" void kernel_launch(void* const* d_in, const int* in_sizes, int n_in,
                              void* d_out, int out_size, void* d_ws, size_t ws_size,
                              hipStream_t stream) {
    const float* x    = (const float*)d_in[0];
    const float* wih0 = (const float*)d_in[1];
    const float* whh0 = (const float*)d_in[2];
    const float* bih0 = (const float*)d_in[3];
    const float* bhh0 = (const float*)d_in[4];
    const float* wih1 = (const float*)d_in[5];
    const float* whh1 = (const float*)d_in[6];
    const float* bih1 = (const float*)d_in[7];
    const float* bhh1 = (const float*)d_in[8];
    const float* wout = (const float*)d_in[9];
    const float* bout = (const float*)d_in[10];
    float* out = (float*)d_out;

    hipLaunchKernelGGL(pack_x, dim3(TT), dim3(256), 0, stream, x);
    hipLaunchKernelGGL(lstm2_fused, dim3(NWG_TOT), dim3(256), 0, stream,
                       x, wih0, whh0, bih0, bhh0, wih1, whh1, bih1, bhh1,
                       wout, bout, out);
}